// Round 8
// baseline (97.092 us; speedup 1.0000x reference)
//
#include <hip/hip_runtime.h>

#define CRGB 64
#define CEV  32
#define CIN  96
#define MID  32
#define HH   256
#define WW   256
#define HW   (HH*WW)

// tile geometry: block = 1024 threads = 16x32 pixels, halo tile 18x34
#define TLH 16
#define TLW 32
#define SRH 18
#define SRW 34
#define SPX (SRH*SRW)        // 612 pixels
#define QSTRIDE (SPX*4)      // floats per channel-quad in LDS (2448)

typedef _Float16 f16x8 __attribute__((ext_vector_type(8)));
typedef float    f32x4 __attribute__((ext_vector_type(4)));

typedef const __attribute__((address_space(1))) float* gas_fp;
typedef __attribute__((address_space(3))) float*       las_fp;

// ws layout (bytes):
//   [0,     36864) : W2f f16 A-frag-linear, k-dim permuted: kappa = g*8+mh*4+r <-> m = mh*16+g*4+r
//   [36864, 43008) : W1f f16 A-frag-linear (natural k-order)
//   [43008, 45312) : b2p f32 [(cg*9+ij)*16 + cc]
#define WS_W2F 0
#define WS_W1F 36864
#define WS_B2P 43008

__global__ __launch_bounds__(256) void prep_kernel(
    const float* __restrict__ W1, const float* __restrict__ W2,
    const float* __restrict__ b2, char* __restrict__ ws)
{
    _Float16* W2f = (_Float16*)(ws + WS_W2F);
    _Float16* W1f = (_Float16*)(ws + WS_W1F);
    float*    b2p = (float*)(ws + WS_B2P);
    const int idx = blockIdx.x * 256 + threadIdx.x;
    if (idx < 18432) {
        const int e   = idx & 7;
        const int ln  = (idx >> 3) & 63;
        const int t   = idx >> 9;             // cg*9+ij, 0..35
        const int ij  = t % 9, cg = t / 9;
        const int c   = cg * 16 + (ln & 15);  // A row = out channel within cg
        const int kap = (ln >> 4) * 8 + e;    // kappa
        const int m   = ((kap >> 2) & 1) * 16 + (kap >> 3) * 4 + (kap & 3);
        W2f[idx] = (_Float16)W2[(c * 9 + ij) * MID + m];
    }
    if (idx < 3072) {
        const int e  = idx & 7;
        const int ln = (idx >> 3) & 63;
        const int t  = idx >> 9;              // ks*2+mh, 0..5
        const int ks = t >> 1, mh = t & 1;
        const int m  = mh * 16 + (ln & 15);
        const int k  = ks * 32 + (ln >> 4) * 8 + e;
        W1f[idx] = (_Float16)W1[m * CIN + k];
    }
    if (idx < 576) {
        const int cc = idx & 15;
        const int t  = idx >> 4;
        const int ij = t % 9, cg = t / 9;
        b2p[idx] = b2[(cg * 16 + cc) * 9 + ij];
    }
}

// Block = 1024 threads (16 waves) = 16x32 px tile, all 64 out channels.
// LDS holds the fp32 halo tile in channel-quad-major layout:
//   srgb[q*QSTRIDE + p*4 + r]  <=>  channel q*4+r at halo pixel p.
// Staged via global_load_lds (wave w stages quad w; 39 insts, fire-and-forget).
// Wave w computes row w; st = column half. One barrier total.
__global__ __launch_bounds__(1024, 1) void fusion_mfma5(
    const float* __restrict__ rgb, const float* __restrict__ ev,
    const float* __restrict__ b1, const char* __restrict__ ws,
    float* __restrict__ out)
{
    __shared__ __align__(16) float srgb[16 * QSTRIDE];   // 156672 B

    const int tid  = threadIdx.x;
    const int wave = tid >> 6;
    const int lane = tid & 63;
    const int l15  = lane & 15;
    const int g    = lane >> 4;

    const int bx = blockIdx.x;
    const int tc = bx & 7, tr = (bx >> 3) & 15, b = bx >> 7;
    const int px0 = tc * TLW, py0 = tr * TLH;

    const float* rgbP = rgb + (size_t)b * CRGB * HW;
    const float* evP  = ev  + (size_t)b * CEV  * HW;
    float*       outP = out + (size_t)b * CRGB * HW;

    const _Float16* W2f = (const _Float16*)(ws + WS_W2F);
    const _Float16* W1f = (const _Float16*)(ws + WS_W1F);
    const float*    b2p = (const float*)(ws + WS_B2P);

    // ---- stage rgb halo tile via global_load_lds (wave w -> channel quad w) --
    // linear LDS index within quad: li = j*64 + lane -> p = li>>2, r = li&3.
    {
        const int q = wave;
        const float* chbase = rgbP + (size_t)(q * 4) * HW;
        float* ldsbase = &srgb[q * QSTRIDE];
#pragma unroll 4
        for (int j = 0; j < 39; ++j) {
            if (j < 38 || lane < 16) {          // 38*64+16 = 2448 = QSTRIDE
                const int li  = j * 64 + lane;
                const int p   = li >> 2, r = li & 3;
                const int row = p / SRW;
                const int col = p - row * SRW;
                int gy = py0 - 1 + row; gy = gy < 0 ? 1 : (gy > HH - 1 ? HH - 2 : gy);
                int gx = px0 - 1 + col; gx = gx < 0 ? 1 : (gx > WW - 1 ? WW - 2 : gx);
                const float* gsrc = chbase + (size_t)r * HW + gy * WW + gx;
                __builtin_amdgcn_global_load_lds(
                    (gas_fp)(const void*)gsrc,
                    (las_fp)(void*)(ldsbase + j * 64), 4, 0, 0);
            }
        }
    }

    // conv1 A-frags + biases + ev B-frags (independent of LDS staging;
    // all in flight together with the gload_lds drain)
    f16x8 a1[6];
#pragma unroll
    for (int t = 0; t < 6; ++t)
        a1[t] = ((const f16x8*)W1f)[t * 64 + lane];
    const f32x4 b1v0 = *(const f32x4*)(b1 + g * 4);
    const f32x4 b1v1 = *(const f32x4*)(b1 + 16 + g * 4);

    const int row_l = wave;                    // this wave's tile row (0..15)
    f16x8 bk2[2];
#pragma unroll
    for (int st = 0; st < 2; ++st) {
        const int col = st * 16 + l15;
        const float* esrc = evP + (size_t)(py0 + row_l) * WW + (px0 + col);
#pragma unroll
        for (int e = 0; e < 8; ++e)
            bk2[st][e] = (_Float16)esrc[(size_t)(g * 8 + e) * HW];
    }

    __syncthreads();   // drains vmcnt (incl. global_load_lds) + barrier

    // ---- conv1 via MFMA: produce conv2 B-frags entirely in registers --------
    f16x8 bfr[2];
#pragma unroll
    for (int st = 0; st < 2; ++st) {
        const int col = st * 16 + l15;
        const int pt  = (row_l + 1) * SRW + col + 1;
        // channels g*8+e: quads g*2, g*2+1 (rgb 0..31); +8 for rgb 32..63
        const f32x4 c0 = *(const f32x4*)&srgb[(g * 2)     * QSTRIDE + pt * 4];
        const f32x4 c1 = *(const f32x4*)&srgb[(g * 2 + 1) * QSTRIDE + pt * 4];
        const f32x4 c2 = *(const f32x4*)&srgb[(8 + g * 2)     * QSTRIDE + pt * 4];
        const f32x4 c3 = *(const f32x4*)&srgb[(8 + g * 2 + 1) * QSTRIDE + pt * 4];
        f16x8 bk0, bk1;
#pragma unroll
        for (int r = 0; r < 4; ++r) {
            bk0[r]     = (_Float16)c0[r];
            bk0[4 + r] = (_Float16)c1[r];
            bk1[r]     = (_Float16)c2[r];
            bk1[4 + r] = (_Float16)c3[r];
        }
        f32x4 d0 = {0.f, 0.f, 0.f, 0.f}, d1 = {0.f, 0.f, 0.f, 0.f};
        d0 = __builtin_amdgcn_mfma_f32_16x16x32_f16(a1[0], bk0, d0, 0, 0, 0);
        d1 = __builtin_amdgcn_mfma_f32_16x16x32_f16(a1[1], bk0, d1, 0, 0, 0);
        d0 = __builtin_amdgcn_mfma_f32_16x16x32_f16(a1[2], bk1, d0, 0, 0, 0);
        d1 = __builtin_amdgcn_mfma_f32_16x16x32_f16(a1[3], bk1, d1, 0, 0, 0);
        d0 = __builtin_amdgcn_mfma_f32_16x16x32_f16(a1[4], bk2[st], d0, 0, 0, 0);
        d1 = __builtin_amdgcn_mfma_f32_16x16x32_f16(a1[5], bk2[st], d1, 0, 0, 0);
        // bias + relu + pack: e = mh*4+r -> kappa = g*8+mh*4+r (matches W2f perm)
        f16x8 bf;
#pragma unroll
        for (int r = 0; r < 4; ++r) {
            float v0 = d0[r] + b1v0[r]; v0 = v0 > 0.f ? v0 : 0.f;
            float v1 = d1[r] + b1v1[r]; v1 = v1 > 0.f ? v1 : 0.f;
            bf[r]     = (_Float16)v0;
            bf[4 + r] = (_Float16)v1;
        }
        bfr[st] = bf;
    }

    // ---- conv2 (MFMA, bias via C-init) + apply from fp32 LDS ----------------
    for (int cg = 0; cg < 4; ++cg) {
        f16x8 a2[9];
        f32x4 ci[9];
#pragma unroll
        for (int ij = 0; ij < 9; ++ij) {
            a2[ij] = ((const f16x8*)W2f)[(cg * 9 + ij) * 64 + lane];
            ci[ij] = *(const f32x4*)(b2p + (cg * 9 + ij) * 16 + g * 4);
        }
        const int qa = cg * 4 + g;   // LDS quad holding channels cg*16+g*4+r
#pragma unroll
        for (int st = 0; st < 2; ++st) {
            const int col = st * 16 + l15;
            float acc0 = 0.f, acc1 = 0.f, acc2 = 0.f, acc3 = 0.f;
#pragma unroll
            for (int ij = 0; ij < 9; ++ij) {
                const f32x4 d = __builtin_amdgcn_mfma_f32_16x16x32_f16(a2[ij], bfr[st], ci[ij], 0, 0, 0);
                const int pt = (row_l + ij / 3) * SRW + col + (ij % 3);
                const f32x4 pv = *(const f32x4*)&srgb[qa * QSTRIDE + pt * 4];
                acc0 = fmaf(d[0], pv[0], acc0);
                acc1 = fmaf(d[1], pv[1], acc1);
                acc2 = fmaf(d[2], pv[2], acc2);
                acc3 = fmaf(d[3], pv[3], acc3);
            }
            float* op = outP + (size_t)(cg * 16 + g * 4) * HW
                             + (size_t)(py0 + row_l) * WW + (px0 + col);
            op[0]      = acc0;
            op[HW]     = acc1;
            op[2 * HW] = acc2;
            op[3 * HW] = acc3;
        }
    }
}

extern "C" void kernel_launch(void* const* d_in, const int* in_sizes, int n_in,
                              void* d_out, int out_size, void* d_ws, size_t ws_size,
                              hipStream_t stream) {
    const float* rgb = (const float*)d_in[0];
    const float* ev  = (const float*)d_in[1];
    const float* W1p = (const float*)d_in[2];
    const float* b1p = (const float*)d_in[3];
    const float* W2p = (const float*)d_in[4];
    const float* b2p = (const float*)d_in[5];
    float* out = (float*)d_out;
    char* ws = (char*)d_ws;

    hipLaunchKernelGGL(prep_kernel, dim3(72), dim3(256), 0, stream, W1p, W2p, b2p, ws);

    const int B = in_sizes[0] / (CRGB * HW);   // = 4
    hipLaunchKernelGGL(fusion_mfma5, dim3(B * 128), dim3(1024), 0, stream,
                       rgb, ev, b1p, ws, out);
}